// Round 8
// baseline (166.845 us; speedup 1.0000x reference)
//
#include <hip/hip_runtime.h>
#include <math.h>

using f32x4   = __attribute__((ext_vector_type(4))) float;
using bf16x8  = __attribute__((ext_vector_type(8))) short;

constexpr int Bb = 2;
constexpr int T  = 2048;
constexpr int D  = 768;
constexpr int H  = 12;
constexpr int Dh = 64;
constexpr int M  = Bb * T;        // 4096
constexpr int NQKV = 3 * D;       // 2304
constexpr int NBH = Bb * H;       // 24
// fold 1/sqrt(Dh) * log2(e) into Q so attention uses exp2 directly
#define SCALE_Q 0.18033688011112042f

// ---------------------------------------------------------------------------
// helpers
// ---------------------------------------------------------------------------
__device__ __forceinline__ unsigned short f2bf(float f) {
    unsigned u = __float_as_uint(f);
    u += 0x7fffu + ((u >> 16) & 1u);      // RNE
    return (unsigned short)(u >> 16);
}

__device__ __forceinline__ ushort4 f2bf4(float4 f) {
    return make_ushort4(f2bf(f.x), f2bf(f.y), f2bf(f.z), f2bf(f.w));
}

// truncate-pack two fp32 -> packed bf16x2 in ONE v_perm_b32:
// result = { hi16(hi_f), hi16(lo_f) }
__device__ __forceinline__ unsigned permpk(float hi_f, float lo_f) {
    return __builtin_amdgcn_perm(__float_as_uint(hi_f), __float_as_uint(lo_f),
                                 0x07060302u);
}

// async global->LDS, 16B per lane; lds base must be wave-uniform (HW scatters
// lane l's data to base + l*16)
__device__ __forceinline__ void async_copy16(const void* g, void* lds_base) {
    __builtin_amdgcn_global_load_lds(
        (const __attribute__((address_space(1))) unsigned int*)g,
        (__attribute__((address_space(3))) unsigned int*)lds_base, 16, 0, 0);
}

// ---------------------------------------------------------------------------
// Prep: fp32 -> bf16 for X, stacked Wqkv, Wo; stack biases (fp32)
// ---------------------------------------------------------------------------
__global__ __launch_bounds__(256) void prep_kernel(
    const float4* __restrict__ x,
    const float4* __restrict__ Wq, const float4* __restrict__ Wk,
    const float4* __restrict__ Wv, const float4* __restrict__ Wo,
    const float* __restrict__ bq, const float* __restrict__ bk, const float* __restrict__ bv,
    ushort4* __restrict__ Xb, ushort4* __restrict__ Wqkvb, ushort4* __restrict__ Wob,
    float* __restrict__ biasS)
{
    const int stride = gridDim.x * 256;
    const int i0 = blockIdx.x * 256 + threadIdx.x;
    const int NX = M * D / 4;       // 786432
    const int NW = D * D / 4;       // 147456
    for (int i = i0; i < NX; i += stride) Xb[i] = f2bf4(x[i]);
    for (int i = i0; i < NW; i += stride) {
        Wqkvb[i]          = f2bf4(Wq[i]);
        Wqkvb[NW + i]     = f2bf4(Wk[i]);
        Wqkvb[2 * NW + i] = f2bf4(Wv[i]);
        Wob[i]            = f2bf4(Wo[i]);
    }
    for (int i = i0; i < D; i += stride) {
        biasS[i]         = bq[i];
        biasS[D + i]     = bk[i];
        biasS[2 * D + i] = bv[i];
    }
}

// ---------------------------------------------------------------------------
// bf16 GEMM (B^T layout): C[m,n] = sum_k A[m,k] * B[n,k] + bias[n]
// TM x 128 tile, BK=64 (128 B rows = 8 x 16B blocks), 256 threads (4 waves),
// 16x16x32 MFMA. LDS rows XOR-swizzled (slot = blk ^ (row&7)) -> fragment
// ds_read_b128 are conflict-free.
// Staging: LDS = A rows [0,TM) then B rows [TM,TM+128), 1 KB chunks
// (8 rows x 128 B) round-robined over waves (wave-uniform bases).
// DB=0: single buffer, stage -> drain -> compute.
// DB=1: double buffer, single barrier per iter (stage(next) issued after the
//       barrier, lands under current compute; next barrier's vmcnt(0) drain
//       guarantees arrival). Measured: helps the latency-bound out-proj
//       (R6), neutral on the QKV GEMM (R7) -> QKV stays DB=0.
// XCD-locality swizzle: groups of 8 consecutive linear block IDs share the
// same col-tile. (gridDim.y must be a multiple of 8.)
// MODE 0: fp32 out [M, Ndim] row-major
// MODE 1: QKV epilogue -> bf16 Q,K head-split [B,H,T,Dh] (Q pre-scaled by
//         SCALE_Q); V written TRANSPOSED [B,H,Dh,T] with keys permuted per
//         32-key group (key h*16+g*4+r -> slot g*8+h*4+r) to match the attn
//         PV MFMA k-slot order.
// ---------------------------------------------------------------------------
template <int MODE, int TM, int DB>
__global__ __launch_bounds__(256) void gemm_bt_kernel(
    const unsigned short* __restrict__ A, const unsigned short* __restrict__ Bm,
    const float* __restrict__ bias, const int Kdim, const int Ndim,
    float* __restrict__ Cout,
    unsigned short* __restrict__ Qo, unsigned short* __restrict__ Ko,
    unsigned short* __restrict__ Vo)
{
    constexpr int IW  = TM / 32;           // acc row-frags per wave
    constexpr int NCH = (TM + 128) / 8;    // 1 KB staging chunks (8 rows each)
    constexpr int TB  = (TM + 128) * 128;  // bytes per LDS buffer
    __shared__ unsigned short Sm[(TM + 128) * 64 * (DB ? 2 : 1)];
    const int tid  = threadIdx.x;
    const int lane = tid & 63, wv = tid >> 6;
    const int l15  = lane & 15, l4 = lane >> 4;
    const int wr   = wv >> 1,  wc = wv & 1;

    // swizzle (gridDim.y must be a multiple of 8)
    const int lin = blockIdx.y * gridDim.x + blockIdx.x;
    const int gx  = (lin >> 3) % gridDim.x;
    const int gy  = (lin / (8 * gridDim.x)) * 8 + (lin & 7);
    const int row0 = gy * TM, col0 = gx * 128;

    auto stage = [&](int k0, int b) {
        #pragma unroll
        for (int ch0 = 0; ch0 < NCH; ch0 += 4) {   // NCH % 4 == 0
            const int ch = ch0 + wv;           // wave-uniform per call
            const int offb = ch * 1024;
            const int off  = offb + lane * 16;
            const int r  = off >> 7;           // row in [0, TM+128)
            const int bl = (off & 127) >> 4;   // 16B block within 128 B row
            const int gc = (bl ^ (r & 7)) << 3;    // swizzled element col
            const unsigned short* src = (r < TM)
                ? A  + (size_t)(row0 + r) * Kdim + k0 + gc
                : Bm + (size_t)(col0 + (r - TM)) * Kdim + k0 + gc;
            async_copy16(src, (char*)Sm + b * TB + offb);
        }
    };

    f32x4 acc[IW][4];
    #pragma unroll
    for (int i = 0; i < IW; ++i)
        #pragma unroll
        for (int j = 0; j < 4; ++j)
            acc[i][j] = (f32x4){0.f, 0.f, 0.f, 0.f};

    if (DB) stage(0, 0);

    for (int k0 = 0, it = 0; k0 < Kdim; k0 += 64, ++it) {
        const int cur = DB ? (it & 1) : 0;
        __syncthreads();                 // DB=0: prev ds_reads done.
                                         // DB=1: buf[cur] staged (vmcnt drain)
                                         //       + buf[cur^1] readers done.
        if (DB) {
            if (k0 + 64 < Kdim) stage(k0 + 64, cur ^ 1);
        } else {
            stage(k0, 0);
            __syncthreads();             // drains vmcnt -> tiles ready
        }
        const char* Sb_ = (const char*)Sm + cur * TB;

        #pragma unroll
        for (int c = 0; c < 2; ++c) {          // k halves of the 64-wide tile
            bf16x8 af[IW], bfr[4];
            #pragma unroll
            for (int i = 0; i < IW; ++i) {
                const int row = wr * (TM / 2) + i * 16 + l15;
                af[i] = *(const bf16x8*)(Sb_ +
                        row * 128 + (((c << 2) + l4) ^ (row & 7)) * 16);
            }
            #pragma unroll
            for (int j = 0; j < 4; ++j) {
                const int row = TM + wc * 64 + j * 16 + l15;
                bfr[j] = *(const bf16x8*)(Sb_ +
                        row * 128 + (((c << 2) + l4) ^ (row & 7)) * 16);
            }
            #pragma unroll
            for (int i = 0; i < IW; ++i)
                #pragma unroll
                for (int j = 0; j < 4; ++j)
                    acc[i][j] = __builtin_amdgcn_mfma_f32_16x16x32_bf16(af[i], bfr[j], acc[i][j], 0, 0, 0);
        }
    }

    // C/D layout: col = lane&15, row = (lane>>4)*4 + reg
    if (MODE == 0) {
        #pragma unroll
        for (int j = 0; j < 4; ++j) {
            const int n = col0 + wc * 64 + j * 16 + l15;
            const float bv_ = bias[n];
            #pragma unroll
            for (int i = 0; i < IW; ++i) {
                #pragma unroll
                for (int r = 0; r < 4; ++r) {
                    const int m = row0 + wr * (TM / 2) + i * 16 + l4 * 4 + r;
                    Cout[(size_t)m * Ndim + n] = acc[i][j][r] + bv_;
                }
            }
        }
    } else {
        #pragma unroll
        for (int j = 0; j < 4; ++j) {
            const int n = col0 + wc * 64 + j * 16 + l15;
            const int which = n / D;           // uniform per block (768 % 128 == 0)
            const int hd = n % D;
            const int h = hd >> 6, d = hd & 63;
            const float bv_ = bias[n];
            if (which == 2) {
                // V transposed [B,H,Dh,T], keys slot-permuted per 32-group:
                // t = h16*16 + g*4 + r  ->  tp = base32 | g*8 + h16*4 + r
                #pragma unroll
                for (int i = 0; i < IW; ++i) {
                    const int m0 = row0 + wr * (TM / 2) + i * 16 + l4 * 4;
                    const int b = m0 >> 11, t = m0 & (T - 1);
                    const int g = (t >> 2) & 3, h16 = (t >> 4) & 1;
                    const int tp = (t & ~31) | (g << 3) | (h16 << 2);
                    float4 v4;
                    v4.x = acc[i][j][0] + bv_; v4.y = acc[i][j][1] + bv_;
                    v4.z = acc[i][j][2] + bv_; v4.w = acc[i][j][3] + bv_;
                    *(ushort4*)&Vo[((size_t)(b * H + h) * Dh + d) * T + tp] = f2bf4(v4);
                }
            } else {
                const float scale = (which == 0) ? SCALE_Q : 1.0f;
                unsigned short* dst = (which == 0) ? Qo : Ko;
                #pragma unroll
                for (int i = 0; i < IW; ++i) {
                    #pragma unroll
                    for (int r = 0; r < 4; ++r) {
                        const int m = row0 + wr * (TM / 2) + i * 16 + l4 * 4 + r;
                        const int b = m >> 11, t = m & (T - 1);
                        dst[((size_t)(b * H + h) * T + t) * Dh + d] =
                            f2bf((acc[i][j][r] + bv_) * scale);
                    }
                }
            }
        }
    }
}

// ---------------------------------------------------------------------------
// Flash attention, KV-split x2. Body is the proven 47.6 us kernel VERBATIM
// (fixed-max softmax, S^T-in-register, v_perm truncate-pack, ones-MFMA
// row-sum, 1 barrier/iter, K/V dbuf via global_load_lds + XOR swizzle).
// Counter evidence (R7: MfmaUtil 23%, VALUBusy 43%, all pipe TOTALS ~10 us
// in a 48.8 us kernel): attn is latency/dependency-bound at 12 waves/CU,
// NOT pipe-bound. Fix: blockIdx.z picks half the key range (16 tiles);
// grid 1536 blocks, 32 KB LDS -> 5 blocks/CU resident = 20 waves/CU
// (1.67x). Fixed-max softmax => partials over disjoint key ranges SUM
// exactly: block writes fp32 o-partial + rowsum to workspace; combine
// kernel normalizes. Failed directions (do not retry): wave K-split (R1),
// QBLK=128 (R3, halved waves), K-from-global per-lane (R4/R5, VMEM
// latency on the critical chain).
// ---------------------------------------------------------------------------
__global__ __launch_bounds__(256) void attn_kernel(
    const unsigned short* __restrict__ Q, const unsigned short* __restrict__ Kg,
    const unsigned short* __restrict__ Vt,
    float* __restrict__ Po, float* __restrict__ PoL)
{
    __shared__ unsigned short Ks[2][64 * 64];
    __shared__ unsigned short Vs[2][64 * 64];
    const int bh = blockIdx.y;
    const int half = blockIdx.z;          // key range [half*1024, +1024)
    const int q0 = blockIdx.x * 64;
    const int tid = threadIdx.x, lane = tid & 63, wv = tid >> 6;
    const int l15 = lane & 15, l4 = lane >> 4;
    const unsigned short* Qp = Q  + (size_t)bh * T * Dh;
    const unsigned short* Kp = Kg + (size_t)bh * T * Dh;
    const unsigned short* Vp = Vt + (size_t)bh * Dh * T;

    // Q fragments: [n=q=l15][k = l4*8 + j], chunk c covers dh c*32..+31
    bf16x8 qf[2];
    #pragma unroll
    for (int c = 0; c < 2; ++c)
        qf[c] = *(const bf16x8*)&Qp[(size_t)(q0 + wv * 16 + l15) * Dh + c * 32 + l4 * 8];

    const short oneb = (short)0x3F80;     // bf16 1.0
    const bf16x8 onesf = {oneb, oneb, oneb, oneb, oneb, oneb, oneb, oneb};

    auto load_tiles = [&](int kt, int buf) {
        #pragma unroll
        for (int i = 0; i < 2; ++i) {
            const int offb = wv * 2048 + i * 1024;
            const int off  = offb + lane * 16;
            const int r = off >> 7;                     // 128 B per row
            const int blk = (off & 127) >> 4;
            const int gc = (blk ^ (r & 7)) << 3;        // swizzled element col
            async_copy16(Kp + (size_t)(kt + r) * Dh + gc, (char*)&Ks[buf][0] + offb);
            async_copy16(Vp + (size_t)r * T + kt + gc,    (char*)&Vs[buf][0] + offb);
        }
    };

    const int NT = T / 128;               // 16 tiles per half
    const int kt0 = half * NT;
    load_tiles(kt0 * 64, 0);
    f32x4 o[4], oL;
    #pragma unroll
    for (int nj = 0; nj < 4; ++nj) o[nj] = (f32x4){0.f, 0.f, 0.f, 0.f};
    oL = (f32x4){0.f, 0.f, 0.f, 0.f};

    for (int it = 0; it < NT; ++it) {
        const int kt64 = kt0 + it;
        const int cur = it & 1;
        __syncthreads();     // K/V(kt64) ready (vmcnt drain); buf cur^1 reads done
        if (it + 1 < NT) load_tiles((kt64 + 1) * 64, cur ^ 1);

        const char* Kb = (const char*)&Ks[cur][0];
        const char* Vb = (const char*)&Vs[cur][0];

        // ---- S^T for k16 tiles 0,1 (keys 0..31) ----
        f32x4 Sa[2] = {(f32x4){0.f,0.f,0.f,0.f}, (f32x4){0.f,0.f,0.f,0.f}};
        #pragma unroll
        for (int c = 0; c < 2; ++c) {
            #pragma unroll
            for (int t = 0; t < 2; ++t) {
                const int row = t * 16 + l15;
                bf16x8 kb = *(const bf16x8*)(Kb + row * 128 + (((c << 2) + l4) ^ (row & 7)) * 16);
                Sa[t] = __builtin_amdgcn_mfma_f32_16x16x32_bf16(kb, qf[c], Sa[t], 0, 0, 0);
            }
        }
        #pragma unroll
        for (int t = 0; t < 2; ++t)
            #pragma unroll
            for (int r = 0; r < 4; ++r)
                Sa[t][r] = __builtin_amdgcn_exp2f(Sa[t][r]);
        union { unsigned u[4]; bf16x8 v; } p0;
        p0.u[0] = permpk(Sa[0][1], Sa[0][0]);
        p0.u[1] = permpk(Sa[0][3], Sa[0][2]);
        p0.u[2] = permpk(Sa[1][1], Sa[1][0]);
        p0.u[3] = permpk(Sa[1][3], Sa[1][2]);

        // ---- S^T for k16 tiles 2,3 (keys 32..63) ----
        f32x4 Sb[2] = {(f32x4){0.f,0.f,0.f,0.f}, (f32x4){0.f,0.f,0.f,0.f}};
        #pragma unroll
        for (int c = 0; c < 2; ++c) {
            #pragma unroll
            for (int t = 0; t < 2; ++t) {
                const int row = (t + 2) * 16 + l15;
                bf16x8 kb = *(const bf16x8*)(Kb + row * 128 + (((c << 2) + l4) ^ (row & 7)) * 16);
                Sb[t] = __builtin_amdgcn_mfma_f32_16x16x32_bf16(kb, qf[c], Sb[t], 0, 0, 0);
            }
        }

        // ---- PV G0 (overlaps exp2 G1) ----
        oL = __builtin_amdgcn_mfma_f32_16x16x32_bf16(p0.v, onesf, oL, 0, 0, 0);
        #pragma unroll
        for (int nj = 0; nj < 4; ++nj) {
            const int row = nj * 16 + l15;
            bf16x8 vb = *(const bf16x8*)(Vb + row * 128 + ((l4) ^ (row & 7)) * 16);
            o[nj] = __builtin_amdgcn_mfma_f32_16x16x32_bf16(p0.v, vb, o[nj], 0, 0, 0);
        }

        #pragma unroll
        for (int t = 0; t < 2; ++t)
            #pragma unroll
            for (int r = 0; r < 4; ++r)
                Sb[t][r] = __builtin_amdgcn_exp2f(Sb[t][r]);
        union { unsigned u[4]; bf16x8 v; } p1;
        p1.u[0] = permpk(Sb[0][1], Sb[0][0]);
        p1.u[1] = permpk(Sb[0][3], Sb[0][2]);
        p1.u[2] = permpk(Sb[1][1], Sb[1][0]);
        p1.u[3] = permpk(Sb[1][3], Sb[1][2]);

        // ---- PV G1 ----
        oL = __builtin_amdgcn_mfma_f32_16x16x32_bf16(p1.v, onesf, oL, 0, 0, 0);
        #pragma unroll
        for (int nj = 0; nj < 4; ++nj) {
            const int row = nj * 16 + l15;
            bf16x8 vb = *(const bf16x8*)(Vb + row * 128 + ((4 + l4) ^ (row & 7)) * 16);
            o[nj] = __builtin_amdgcn_mfma_f32_16x16x32_bf16(p1.v, vb, o[nj], 0, 0, 0);
        }
    }

    // write fp32 partials: Po[half][bh][t][64], PoL[half][bh][t]
    const size_t base = (size_t)(half * NBH + bh) * T;
    #pragma unroll
    for (int r = 0; r < 4; ++r) {
        const int t = q0 + wv * 16 + l4 * 4 + r;
        #pragma unroll
        for (int nj = 0; nj < 4; ++nj)
            Po[(base + t) * 64 + nj * 16 + l15] = o[nj][r];
        if (l15 == 0) PoL[base + t] = oL[r];   // all 16 cols of oL identical
    }
}

// ---------------------------------------------------------------------------
// Combine: Ctx[b,t,h*64+d] = (Po0+Po1)/(PoL0+PoL1), bf16.
// ---------------------------------------------------------------------------
__global__ __launch_bounds__(256) void combine_kernel(
    const float4* __restrict__ Po, const float* __restrict__ PoL,
    unsigned short* __restrict__ Ctx)
{
    const int idx = blockIdx.x * 256 + threadIdx.x;   // NBH*T*16 total
    const int d4 = idx & 15;
    const int rem = idx >> 4;            // bh*T + t
    const int t = rem & (T - 1), bh = rem >> 11;
    const float4 a = Po[(size_t)rem * 16 + d4];
    const float4 c = Po[(size_t)NBH * T * 16 + (size_t)rem * 16 + d4];
    const float inv = 1.0f / (PoL[rem] + PoL[NBH * T + rem]);
    const int b = bh / H, h = bh % H;
    float4 v;
    v.x = (a.x + c.x) * inv; v.y = (a.y + c.y) * inv;
    v.z = (a.z + c.z) * inv; v.w = (a.w + c.w) * inv;
    *(ushort4*)&Ctx[(size_t)(b * T + t) * D + h * 64 + d4 * 4] = f2bf4(v);
}

// ---------------------------------------------------------------------------
extern "C" void kernel_launch(void* const* d_in, const int* in_sizes, int n_in,
                              void* d_out, int out_size, void* d_ws, size_t ws_size,
                              hipStream_t stream) {
    const float* x  = (const float*)d_in[0];
    const float* Wq = (const float*)d_in[1];
    const float* bq = (const float*)d_in[2];
    const float* Wk = (const float*)d_in[3];
    const float* bk = (const float*)d_in[4];
    const float* Wv = (const float*)d_in[5];
    const float* bv = (const float*)d_in[6];
    const float* Wo = (const float*)d_in[7];
    const float* bo = (const float*)d_in[8];
    float* out = (float*)d_out;

    // workspace carve-up (~60 MB total)
    char* w = (char*)d_ws;
    auto alloc = [&](size_t bytes) {
        char* p = w; w += (bytes + 255) & ~(size_t)255; return p;
    };
    unsigned short* Xb    = (unsigned short*)alloc((size_t)M * D * 2);
    unsigned short* Wqkvb = (unsigned short*)alloc((size_t)NQKV * D * 2);
    unsigned short* Wob   = (unsigned short*)alloc((size_t)D * D * 2);
    float*          biasS = (float*)alloc((size_t)NQKV * 4);
    unsigned short* Qb    = (unsigned short*)alloc((size_t)M * D * 2);
    unsigned short* Kb    = (unsigned short*)alloc((size_t)M * D * 2);
    unsigned short* Vtb   = (unsigned short*)alloc((size_t)M * D * 2);
    unsigned short* Ctxb  = (unsigned short*)alloc((size_t)M * D * 2);
    float*          Po    = (float*)alloc((size_t)2 * NBH * T * 64 * 4);
    float*          PoL   = (float*)alloc((size_t)2 * NBH * T * 4);

    prep_kernel<<<1024, 256, 0, stream>>>(
        (const float4*)x, (const float4*)Wq, (const float4*)Wk, (const float4*)Wv,
        (const float4*)Wo, bq, bk, bv,
        (ushort4*)Xb, (ushort4*)Wqkvb, (ushort4*)Wob, biasS);

    // QKV GEMM: proven single-buffer path (DB=0; DB=1 was neutral, R7)
    gemm_bt_kernel<1, 128, 0><<<dim3(NQKV / 128, M / 128), 256, 0, stream>>>(
        Xb, Wqkvb, biasS, D, NQKV, nullptr, Qb, Kb, Vtb);

    // attention, KV-split x2: grid (32, 24, 2) = 1536 blocks, 5 blocks/CU
    attn_kernel<<<dim3(T / 64, NBH, 2), 256, 0, stream>>>(Qb, Kb, Vtb, Po, PoL);

    // combine partials -> Ctx bf16
    combine_kernel<<<NBH * T * 16 / 256, 256, 0, stream>>>(
        (const float4*)Po, PoL, Ctxb);

    // out-projection: TM=32 + DB=1 (validated R6)
    gemm_bt_kernel<0, 32, 1><<<dim3(D / 128, M / 32), 256, 0, stream>>>(
        Ctxb, Wob, bo, D, D, out, nullptr, nullptr, nullptr);
}

// Round 9
// 161.190 us; speedup vs baseline: 1.0351x; 1.0351x over previous
//
#include <hip/hip_runtime.h>
#include <math.h>

using f32x4   = __attribute__((ext_vector_type(4))) float;
using bf16x8  = __attribute__((ext_vector_type(8))) short;

constexpr int Bb = 2;
constexpr int T  = 2048;
constexpr int D  = 768;
constexpr int H  = 12;
constexpr int Dh = 64;
constexpr int M  = Bb * T;        // 4096
constexpr int NQKV = 3 * D;       // 2304
// fold 1/sqrt(Dh) * log2(e) into Q so attention uses exp2 directly
#define SCALE_Q 0.18033688011112042f

// ---------------------------------------------------------------------------
// helpers
// ---------------------------------------------------------------------------
__device__ __forceinline__ unsigned short f2bf(float f) {
    unsigned u = __float_as_uint(f);
    u += 0x7fffu + ((u >> 16) & 1u);      // RNE
    return (unsigned short)(u >> 16);
}

__device__ __forceinline__ ushort4 f2bf4(float4 f) {
    return make_ushort4(f2bf(f.x), f2bf(f.y), f2bf(f.z), f2bf(f.w));
}

// truncate-pack two fp32 -> packed bf16x2 in ONE v_perm_b32:
// result = { hi16(hi_f), hi16(lo_f) }
__device__ __forceinline__ unsigned permpk(float hi_f, float lo_f) {
    return __builtin_amdgcn_perm(__float_as_uint(hi_f), __float_as_uint(lo_f),
                                 0x07060302u);
}

// async global->LDS, 16B per lane; lds base must be wave-uniform (HW scatters
// lane l's data to base + l*16)
__device__ __forceinline__ void async_copy16(const void* g, void* lds_base) {
    __builtin_amdgcn_global_load_lds(
        (const __attribute__((address_space(1))) unsigned int*)g,
        (__attribute__((address_space(3))) unsigned int*)lds_base, 16, 0, 0);
}

// ---------------------------------------------------------------------------
// Prep: fp32 -> bf16 for X, stacked Wqkv, Wo; stack biases (fp32)
// ---------------------------------------------------------------------------
__global__ __launch_bounds__(256) void prep_kernel(
    const float4* __restrict__ x,
    const float4* __restrict__ Wq, const float4* __restrict__ Wk,
    const float4* __restrict__ Wv, const float4* __restrict__ Wo,
    const float* __restrict__ bq, const float* __restrict__ bk, const float* __restrict__ bv,
    ushort4* __restrict__ Xb, ushort4* __restrict__ Wqkvb, ushort4* __restrict__ Wob,
    float* __restrict__ biasS)
{
    const int stride = gridDim.x * 256;
    const int i0 = blockIdx.x * 256 + threadIdx.x;
    const int NX = M * D / 4;       // 786432
    const int NW = D * D / 4;       // 147456
    for (int i = i0; i < NX; i += stride) Xb[i] = f2bf4(x[i]);
    for (int i = i0; i < NW; i += stride) {
        Wqkvb[i]          = f2bf4(Wq[i]);
        Wqkvb[NW + i]     = f2bf4(Wk[i]);
        Wqkvb[2 * NW + i] = f2bf4(Wv[i]);
        Wob[i]            = f2bf4(Wo[i]);
    }
    for (int i = i0; i < D; i += stride) {
        biasS[i]         = bq[i];
        biasS[D + i]     = bk[i];
        biasS[2 * D + i] = bv[i];
    }
}

// ---------------------------------------------------------------------------
// bf16 GEMM (B^T layout): C[m,n] = sum_k A[m,k] * B[n,k] + bias[n]
// TM x 128 tile, BK=64 (128 B rows = 8 x 16B blocks), 256 threads (4 waves),
// 16x16x32 MFMA. LDS rows XOR-swizzled (slot = blk ^ (row&7)) -> fragment
// ds_read_b128 are conflict-free.
// Staging: LDS = A rows [0,TM) then B rows [TM,TM+128), 1 KB chunks
// (8 rows x 128 B) round-robined over waves (wave-uniform bases).
// DB=0: single buffer, stage -> drain -> compute.
// DB=1: double buffer, single barrier per iter (stage(next) issued after the
//       barrier, lands under current compute; next barrier's vmcnt(0) drain
//       guarantees arrival). Measured: helps the latency-bound out-proj
//       (R6), neutral on the QKV GEMM (R7) -> QKV stays DB=0.
// TM sweep (measured): more blocks wins for these small GEMMs -> QKV TM=64
// (1152 blocks = 4.5/CU; was TM=128 @ 2.25/CU), out-proj TM=32.
// XCD-locality swizzle: groups of 8 consecutive linear block IDs share the
// same col-tile. (gridDim.y must be a multiple of 8.)
// MODE 0: fp32 out [M, Ndim] row-major
// MODE 1: QKV epilogue -> bf16 Q,K head-split [B,H,T,Dh] (Q pre-scaled by
//         SCALE_Q); V written TRANSPOSED [B,H,Dh,T] with keys permuted per
//         32-key group (key h*16+g*4+r -> slot g*8+h*4+r) to match the attn
//         PV MFMA k-slot order.
// ---------------------------------------------------------------------------
template <int MODE, int TM, int DB>
__global__ __launch_bounds__(256) void gemm_bt_kernel(
    const unsigned short* __restrict__ A, const unsigned short* __restrict__ Bm,
    const float* __restrict__ bias, const int Kdim, const int Ndim,
    float* __restrict__ Cout,
    unsigned short* __restrict__ Qo, unsigned short* __restrict__ Ko,
    unsigned short* __restrict__ Vo)
{
    constexpr int IW  = TM / 32;           // acc row-frags per wave
    constexpr int NCH = (TM + 128) / 8;    // 1 KB staging chunks (8 rows each)
    constexpr int TB  = (TM + 128) * 128;  // bytes per LDS buffer
    __shared__ unsigned short Sm[(TM + 128) * 64 * (DB ? 2 : 1)];
    const int tid  = threadIdx.x;
    const int lane = tid & 63, wv = tid >> 6;
    const int l15  = lane & 15, l4 = lane >> 4;
    const int wr   = wv >> 1,  wc = wv & 1;

    // swizzle (gridDim.y must be a multiple of 8)
    const int lin = blockIdx.y * gridDim.x + blockIdx.x;
    const int gx  = (lin >> 3) % gridDim.x;
    const int gy  = (lin / (8 * gridDim.x)) * 8 + (lin & 7);
    const int row0 = gy * TM, col0 = gx * 128;

    auto stage = [&](int k0, int b) {
        #pragma unroll
        for (int ch0 = 0; ch0 < NCH; ch0 += 4) {   // NCH % 4 == 0
            const int ch = ch0 + wv;           // wave-uniform per call
            const int offb = ch * 1024;
            const int off  = offb + lane * 16;
            const int r  = off >> 7;           // row in [0, TM+128)
            const int bl = (off & 127) >> 4;   // 16B block within 128 B row
            const int gc = (bl ^ (r & 7)) << 3;    // swizzled element col
            const unsigned short* src = (r < TM)
                ? A  + (size_t)(row0 + r) * Kdim + k0 + gc
                : Bm + (size_t)(col0 + (r - TM)) * Kdim + k0 + gc;
            async_copy16(src, (char*)Sm + b * TB + offb);
        }
    };

    f32x4 acc[IW][4];
    #pragma unroll
    for (int i = 0; i < IW; ++i)
        #pragma unroll
        for (int j = 0; j < 4; ++j)
            acc[i][j] = (f32x4){0.f, 0.f, 0.f, 0.f};

    if (DB) stage(0, 0);

    for (int k0 = 0, it = 0; k0 < Kdim; k0 += 64, ++it) {
        const int cur = DB ? (it & 1) : 0;
        __syncthreads();                 // DB=0: prev ds_reads done.
                                         // DB=1: buf[cur] staged (vmcnt drain)
                                         //       + buf[cur^1] readers done.
        if (DB) {
            if (k0 + 64 < Kdim) stage(k0 + 64, cur ^ 1);
        } else {
            stage(k0, 0);
            __syncthreads();             // drains vmcnt -> tiles ready
        }
        const char* Sb_ = (const char*)Sm + cur * TB;

        #pragma unroll
        for (int c = 0; c < 2; ++c) {          // k halves of the 64-wide tile
            bf16x8 af[IW], bfr[4];
            #pragma unroll
            for (int i = 0; i < IW; ++i) {
                const int row = wr * (TM / 2) + i * 16 + l15;
                af[i] = *(const bf16x8*)(Sb_ +
                        row * 128 + (((c << 2) + l4) ^ (row & 7)) * 16);
            }
            #pragma unroll
            for (int j = 0; j < 4; ++j) {
                const int row = TM + wc * 64 + j * 16 + l15;
                bfr[j] = *(const bf16x8*)(Sb_ +
                        row * 128 + (((c << 2) + l4) ^ (row & 7)) * 16);
            }
            #pragma unroll
            for (int i = 0; i < IW; ++i)
                #pragma unroll
                for (int j = 0; j < 4; ++j)
                    acc[i][j] = __builtin_amdgcn_mfma_f32_16x16x32_bf16(af[i], bfr[j], acc[i][j], 0, 0, 0);
        }
    }

    // C/D layout: col = lane&15, row = (lane>>4)*4 + reg
    if (MODE == 0) {
        #pragma unroll
        for (int j = 0; j < 4; ++j) {
            const int n = col0 + wc * 64 + j * 16 + l15;
            const float bv_ = bias[n];
            #pragma unroll
            for (int i = 0; i < IW; ++i) {
                #pragma unroll
                for (int r = 0; r < 4; ++r) {
                    const int m = row0 + wr * (TM / 2) + i * 16 + l4 * 4 + r;
                    Cout[(size_t)m * Ndim + n] = acc[i][j][r] + bv_;
                }
            }
        }
    } else {
        #pragma unroll
        for (int j = 0; j < 4; ++j) {
            const int n = col0 + wc * 64 + j * 16 + l15;
            const int which = n / D;           // uniform per block (768 % 128 == 0)
            const int hd = n % D;
            const int h = hd >> 6, d = hd & 63;
            const float bv_ = bias[n];
            if (which == 2) {
                // V transposed [B,H,Dh,T], keys slot-permuted per 32-group:
                // t = h16*16 + g*4 + r  ->  tp = base32 | g*8 + h16*4 + r
                #pragma unroll
                for (int i = 0; i < IW; ++i) {
                    const int m0 = row0 + wr * (TM / 2) + i * 16 + l4 * 4;
                    const int b = m0 >> 11, t = m0 & (T - 1);
                    const int g = (t >> 2) & 3, h16 = (t >> 4) & 1;
                    const int tp = (t & ~31) | (g << 3) | (h16 << 2);
                    float4 v4;
                    v4.x = acc[i][j][0] + bv_; v4.y = acc[i][j][1] + bv_;
                    v4.z = acc[i][j][2] + bv_; v4.w = acc[i][j][3] + bv_;
                    *(ushort4*)&Vo[((size_t)(b * H + h) * Dh + d) * T + tp] = f2bf4(v4);
                }
            } else {
                const float scale = (which == 0) ? SCALE_Q : 1.0f;
                unsigned short* dst = (which == 0) ? Qo : Ko;
                #pragma unroll
                for (int i = 0; i < IW; ++i) {
                    #pragma unroll
                    for (int r = 0; r < 4; ++r) {
                        const int m = row0 + wr * (TM / 2) + i * 16 + l4 * 4 + r;
                        const int b = m >> 11, t = m & (T - 1);
                        dst[((size_t)(b * H + h) * T + t) * Dh + d] =
                            f2bf((acc[i][j][r] + bv_) * scale);
                    }
                }
            }
        }
    }
}

// ---------------------------------------------------------------------------
// Flash attention (proven ~47.6 us version, verbatim — FROZEN).
// Fixed-max softmax, S^T-in-register (16x16 shape), v_perm truncate-pack,
// phase-interleaved, ones-MFMA row-sum, 1 barrier/iter, K/V double-buffered
// via global_load_lds with XOR-swizzled 16B blocks.
// Bottleneck (R8 diagnosis): per-CU LDS-read BW — all 4 waves read the SAME
// 16 KB K/V tile (addresses wave-independent) -> 4x read redundancy, ~25 us
// LDS floor. Failed directions (do not retry): wave K-split (R1, wrong
// results), QBLK=128 (R3, occupancy), K-from-global per-lane (R4/R5, VMEM
// amplification), KV-split x2 + combine (R8, neutral attn + combine cost).
// ---------------------------------------------------------------------------
__global__ __launch_bounds__(256) void attn_kernel(
    const unsigned short* __restrict__ Q, const unsigned short* __restrict__ Kg,
    const unsigned short* __restrict__ Vt, unsigned short* __restrict__ Ctx)
{
    __shared__ unsigned short Ks[2][64 * 64];
    __shared__ unsigned short Vs[2][64 * 64];
    const int bh = blockIdx.y;
    const int q0 = blockIdx.x * 64;
    const int tid = threadIdx.x, lane = tid & 63, wv = tid >> 6;
    const int l15 = lane & 15, l4 = lane >> 4;
    const unsigned short* Qp = Q  + (size_t)bh * T * Dh;
    const unsigned short* Kp = Kg + (size_t)bh * T * Dh;
    const unsigned short* Vp = Vt + (size_t)bh * Dh * T;

    // Q fragments: [n=q=l15][k = l4*8 + j], chunk c covers dh c*32..+31
    bf16x8 qf[2];
    #pragma unroll
    for (int c = 0; c < 2; ++c)
        qf[c] = *(const bf16x8*)&Qp[(size_t)(q0 + wv * 16 + l15) * Dh + c * 32 + l4 * 8];

    const short oneb = (short)0x3F80;     // bf16 1.0
    const bf16x8 onesf = {oneb, oneb, oneb, oneb, oneb, oneb, oneb, oneb};

    auto load_tiles = [&](int kt, int buf) {
        #pragma unroll
        for (int i = 0; i < 2; ++i) {
            const int offb = wv * 2048 + i * 1024;
            const int off  = offb + lane * 16;
            const int r = off >> 7;                     // 128 B per row
            const int blk = (off & 127) >> 4;
            const int gc = (blk ^ (r & 7)) << 3;        // swizzled element col
            async_copy16(Kp + (size_t)(kt + r) * Dh + gc, (char*)&Ks[buf][0] + offb);
            async_copy16(Vp + (size_t)r * T + kt + gc,    (char*)&Vs[buf][0] + offb);
        }
    };

    load_tiles(0, 0);
    f32x4 o[4], oL;
    #pragma unroll
    for (int nj = 0; nj < 4; ++nj) o[nj] = (f32x4){0.f, 0.f, 0.f, 0.f};
    oL = (f32x4){0.f, 0.f, 0.f, 0.f};

    for (int kt64 = 0; kt64 < T / 64; ++kt64) {
        const int cur = kt64 & 1;
        __syncthreads();     // K/V(kt64) ready (vmcnt drain); buf cur^1 reads done
        if (kt64 + 1 < T / 64) load_tiles((kt64 + 1) * 64, cur ^ 1);

        const char* Kb = (const char*)&Ks[cur][0];
        const char* Vb = (const char*)&Vs[cur][0];

        // ---- S^T for k16 tiles 0,1 (keys 0..31) ----
        f32x4 Sa[2] = {(f32x4){0.f,0.f,0.f,0.f}, (f32x4){0.f,0.f,0.f,0.f}};
        #pragma unroll
        for (int c = 0; c < 2; ++c) {
            #pragma unroll
            for (int t = 0; t < 2; ++t) {
                const int row = t * 16 + l15;
                bf16x8 kb = *(const bf16x8*)(Kb + row * 128 + (((c << 2) + l4) ^ (row & 7)) * 16);
                Sa[t] = __builtin_amdgcn_mfma_f32_16x16x32_bf16(kb, qf[c], Sa[t], 0, 0, 0);
            }
        }
        #pragma unroll
        for (int t = 0; t < 2; ++t)
            #pragma unroll
            for (int r = 0; r < 4; ++r)
                Sa[t][r] = __builtin_amdgcn_exp2f(Sa[t][r]);
        union { unsigned u[4]; bf16x8 v; } p0;
        p0.u[0] = permpk(Sa[0][1], Sa[0][0]);
        p0.u[1] = permpk(Sa[0][3], Sa[0][2]);
        p0.u[2] = permpk(Sa[1][1], Sa[1][0]);
        p0.u[3] = permpk(Sa[1][3], Sa[1][2]);

        // ---- S^T for k16 tiles 2,3 (keys 32..63) ----
        f32x4 Sb[2] = {(f32x4){0.f,0.f,0.f,0.f}, (f32x4){0.f,0.f,0.f,0.f}};
        #pragma unroll
        for (int c = 0; c < 2; ++c) {
            #pragma unroll
            for (int t = 0; t < 2; ++t) {
                const int row = (t + 2) * 16 + l15;
                bf16x8 kb = *(const bf16x8*)(Kb + row * 128 + (((c << 2) + l4) ^ (row & 7)) * 16);
                Sb[t] = __builtin_amdgcn_mfma_f32_16x16x32_bf16(kb, qf[c], Sb[t], 0, 0, 0);
            }
        }

        // ---- PV G0 (overlaps exp2 G1) ----
        oL = __builtin_amdgcn_mfma_f32_16x16x32_bf16(p0.v, onesf, oL, 0, 0, 0);
        #pragma unroll
        for (int nj = 0; nj < 4; ++nj) {
            const int row = nj * 16 + l15;
            bf16x8 vb = *(const bf16x8*)(Vb + row * 128 + ((l4) ^ (row & 7)) * 16);
            o[nj] = __builtin_amdgcn_mfma_f32_16x16x32_bf16(p0.v, vb, o[nj], 0, 0, 0);
        }

        #pragma unroll
        for (int t = 0; t < 2; ++t)
            #pragma unroll
            for (int r = 0; r < 4; ++r)
                Sb[t][r] = __builtin_amdgcn_exp2f(Sb[t][r]);
        union { unsigned u[4]; bf16x8 v; } p1;
        p1.u[0] = permpk(Sb[0][1], Sb[0][0]);
        p1.u[1] = permpk(Sb[0][3], Sb[0][2]);
        p1.u[2] = permpk(Sb[1][1], Sb[1][0]);
        p1.u[3] = permpk(Sb[1][3], Sb[1][2]);

        // ---- PV G1 ----
        oL = __builtin_amdgcn_mfma_f32_16x16x32_bf16(p1.v, onesf, oL, 0, 0, 0);
        #pragma unroll
        for (int nj = 0; nj < 4; ++nj) {
            const int row = nj * 16 + l15;
            bf16x8 vb = *(const bf16x8*)(Vb + row * 128 + ((4 + l4) ^ (row & 7)) * 16);
            o[nj] = __builtin_amdgcn_mfma_f32_16x16x32_bf16(p1.v, vb, o[nj], 0, 0, 0);
        }
    }

    // normalize, write ctx bf16 [B, T, D]
    const int b = bh / H, h = bh % H;
    #pragma unroll
    for (int r = 0; r < 4; ++r) {
        const float inv = 1.0f / oL[r];
        const int t = q0 + wv * 16 + l4 * 4 + r;
        #pragma unroll
        for (int nj = 0; nj < 4; ++nj) {
            const int col = h * 64 + nj * 16 + l15;
            Ctx[(size_t)(b * T + t) * D + col] = f2bf(o[nj][r] * inv);
        }
    }
}

// ---------------------------------------------------------------------------
extern "C" void kernel_launch(void* const* d_in, const int* in_sizes, int n_in,
                              void* d_out, int out_size, void* d_ws, size_t ws_size,
                              hipStream_t stream) {
    const float* x  = (const float*)d_in[0];
    const float* Wq = (const float*)d_in[1];
    const float* bq = (const float*)d_in[2];
    const float* Wk = (const float*)d_in[3];
    const float* bk = (const float*)d_in[4];
    const float* Wv = (const float*)d_in[5];
    const float* bv = (const float*)d_in[6];
    const float* Wo = (const float*)d_in[7];
    const float* bo = (const float*)d_in[8];
    float* out = (float*)d_out;

    // workspace carve-up (~34 MB total)
    char* w = (char*)d_ws;
    auto alloc = [&](size_t bytes) {
        char* p = w; w += (bytes + 255) & ~(size_t)255; return p;
    };
    unsigned short* Xb    = (unsigned short*)alloc((size_t)M * D * 2);
    unsigned short* Wqkvb = (unsigned short*)alloc((size_t)NQKV * D * 2);
    unsigned short* Wob   = (unsigned short*)alloc((size_t)D * D * 2);
    float*          biasS = (float*)alloc((size_t)NQKV * 4);
    unsigned short* Qb    = (unsigned short*)alloc((size_t)M * D * 2);
    unsigned short* Kb    = (unsigned short*)alloc((size_t)M * D * 2);
    unsigned short* Vtb   = (unsigned short*)alloc((size_t)M * D * 2);
    unsigned short* Ctxb  = (unsigned short*)alloc((size_t)M * D * 2);

    prep_kernel<<<1024, 256, 0, stream>>>(
        (const float4*)x, (const float4*)Wq, (const float4*)Wk, (const float4*)Wv,
        (const float4*)Wo, bq, bk, bv,
        (ushort4*)Xb, (ushort4*)Wqkvb, (ushort4*)Wob, biasS);

    // QKV GEMM: TM=64, DB=0 -> grid (18, 64) = 1152 blocks = 4.5/CU (was
    // TM=128 @ 576 blocks = 2.25/CU; TM sweep on out-proj showed block count
    // dominates). 24 KB LDS -> no residency cap. Same proven template.
    gemm_bt_kernel<1, 64, 0><<<dim3(NQKV / 128, M / 64), 256, 0, stream>>>(
        Xb, Wqkvb, biasS, D, NQKV, nullptr, Qb, Kb, Vtb);

    // attention: proven kernel (frozen), grid (32, 24) = 768 blocks (3/CU)
    attn_kernel<<<dim3(T / 64, Bb * H), 256, 0, stream>>>(Qb, Kb, Vtb, Ctxb);

    // out-projection: TM=32 + DB=1 (best measured, R6)
    gemm_bt_kernel<0, 32, 1><<<dim3(D / 128, M / 32), 256, 0, stream>>>(
        Ctxb, Wob, bo, D, D, out, nullptr, nullptr, nullptr);
}

// Round 10
// 155.464 us; speedup vs baseline: 1.0732x; 1.0368x over previous
//
#include <hip/hip_runtime.h>
#include <math.h>

using f32x4   = __attribute__((ext_vector_type(4))) float;
using bf16x8  = __attribute__((ext_vector_type(8))) short;

constexpr int Bb = 2;
constexpr int T  = 2048;
constexpr int D  = 768;
constexpr int H  = 12;
constexpr int Dh = 64;
constexpr int M  = Bb * T;        // 4096
constexpr int NQKV = 3 * D;       // 2304
// fold 1/sqrt(Dh) * log2(e) into Q so attention uses exp2 directly
#define SCALE_Q 0.18033688011112042f

// ---------------------------------------------------------------------------
// helpers
// ---------------------------------------------------------------------------
__device__ __forceinline__ unsigned short f2bf(float f) {
    unsigned u = __float_as_uint(f);
    u += 0x7fffu + ((u >> 16) & 1u);      // RNE
    return (unsigned short)(u >> 16);
}

__device__ __forceinline__ ushort4 f2bf4(float4 f) {
    return make_ushort4(f2bf(f.x), f2bf(f.y), f2bf(f.z), f2bf(f.w));
}

// truncate-pack two fp32 -> packed bf16x2 in ONE v_perm_b32:
// result = { hi16(hi_f), hi16(lo_f) }
__device__ __forceinline__ unsigned permpk(float hi_f, float lo_f) {
    return __builtin_amdgcn_perm(__float_as_uint(hi_f), __float_as_uint(lo_f),
                                 0x07060302u);
}

// async global->LDS, 16B per lane; lds base must be wave-uniform (HW scatters
// lane l's data to base + l*16)
__device__ __forceinline__ void async_copy16(const void* g, void* lds_base) {
    __builtin_amdgcn_global_load_lds(
        (const __attribute__((address_space(1))) unsigned int*)g,
        (__attribute__((address_space(3))) unsigned int*)lds_base, 16, 0, 0);
}

// ---------------------------------------------------------------------------
// Prep: fp32 -> bf16 for X, stacked Wqkv, Wo; stack biases (fp32)
// ---------------------------------------------------------------------------
__global__ __launch_bounds__(256) void prep_kernel(
    const float4* __restrict__ x,
    const float4* __restrict__ Wq, const float4* __restrict__ Wk,
    const float4* __restrict__ Wv, const float4* __restrict__ Wo,
    const float* __restrict__ bq, const float* __restrict__ bk, const float* __restrict__ bv,
    ushort4* __restrict__ Xb, ushort4* __restrict__ Wqkvb, ushort4* __restrict__ Wob,
    float* __restrict__ biasS)
{
    const int stride = gridDim.x * 256;
    const int i0 = blockIdx.x * 256 + threadIdx.x;
    const int NX = M * D / 4;       // 786432
    const int NW = D * D / 4;       // 147456
    for (int i = i0; i < NX; i += stride) Xb[i] = f2bf4(x[i]);
    for (int i = i0; i < NW; i += stride) {
        Wqkvb[i]          = f2bf4(Wq[i]);
        Wqkvb[NW + i]     = f2bf4(Wk[i]);
        Wqkvb[2 * NW + i] = f2bf4(Wv[i]);
        Wob[i]            = f2bf4(Wo[i]);
    }
    for (int i = i0; i < D; i += stride) {
        biasS[i]         = bq[i];
        biasS[D + i]     = bk[i];
        biasS[2 * D + i] = bv[i];
    }
}

// ---------------------------------------------------------------------------
// bf16 GEMM (B^T layout): C[m,n] = sum_k A[m,k] * B[n,k] + bias[n]
// TM x 128 tile, BK=64 (128 B rows = 8 x 16B blocks), 256 threads (4 waves),
// 16x16x32 MFMA. LDS rows XOR-swizzled (slot = blk ^ (row&7)) -> fragment
// ds_read_b128 are conflict-free.
// Config search CLOSED (measured): QKV = TM=128/DB=0 (TM=64 R9: +5us;
// DB=1 R7: neutral). Out-proj = TM=32/DB=1 (TM=64/128 R2/R3: slower;
// DB=1 R6: helps this latency-bound small GEMM).
// XCD-locality swizzle: groups of 8 consecutive linear block IDs share the
// same col-tile. (gridDim.y must be a multiple of 8.)
// MODE 0: fp32 out [M, Ndim] row-major
// MODE 1: QKV epilogue -> bf16 Q,K head-split [B,H,T,Dh] (Q pre-scaled by
//         SCALE_Q); V written TRANSPOSED [B,H,Dh,T] with keys permuted per
//         32-key group (key h*16+g*4+r -> slot g*8+h*4+r) to match the attn
//         PV MFMA k-slot order.
// ---------------------------------------------------------------------------
template <int MODE, int TM, int DB>
__global__ __launch_bounds__(256) void gemm_bt_kernel(
    const unsigned short* __restrict__ A, const unsigned short* __restrict__ Bm,
    const float* __restrict__ bias, const int Kdim, const int Ndim,
    float* __restrict__ Cout,
    unsigned short* __restrict__ Qo, unsigned short* __restrict__ Ko,
    unsigned short* __restrict__ Vo)
{
    constexpr int IW  = TM / 32;           // acc row-frags per wave
    constexpr int NCH = (TM + 128) / 8;    // 1 KB staging chunks (8 rows each)
    constexpr int TB  = (TM + 128) * 128;  // bytes per LDS buffer
    __shared__ unsigned short Sm[(TM + 128) * 64 * (DB ? 2 : 1)];
    const int tid  = threadIdx.x;
    const int lane = tid & 63, wv = tid >> 6;
    const int l15  = lane & 15, l4 = lane >> 4;
    const int wr   = wv >> 1,  wc = wv & 1;

    // swizzle (gridDim.y must be a multiple of 8)
    const int lin = blockIdx.y * gridDim.x + blockIdx.x;
    const int gx  = (lin >> 3) % gridDim.x;
    const int gy  = (lin / (8 * gridDim.x)) * 8 + (lin & 7);
    const int row0 = gy * TM, col0 = gx * 128;

    auto stage = [&](int k0, int b) {
        #pragma unroll
        for (int ch0 = 0; ch0 < NCH; ch0 += 4) {   // NCH % 4 == 0
            const int ch = ch0 + wv;           // wave-uniform per call
            const int offb = ch * 1024;
            const int off  = offb + lane * 16;
            const int r  = off >> 7;           // row in [0, TM+128)
            const int bl = (off & 127) >> 4;   // 16B block within 128 B row
            const int gc = (bl ^ (r & 7)) << 3;    // swizzled element col
            const unsigned short* src = (r < TM)
                ? A  + (size_t)(row0 + r) * Kdim + k0 + gc
                : Bm + (size_t)(col0 + (r - TM)) * Kdim + k0 + gc;
            async_copy16(src, (char*)Sm + b * TB + offb);
        }
    };

    f32x4 acc[IW][4];
    #pragma unroll
    for (int i = 0; i < IW; ++i)
        #pragma unroll
        for (int j = 0; j < 4; ++j)
            acc[i][j] = (f32x4){0.f, 0.f, 0.f, 0.f};

    if (DB) stage(0, 0);

    for (int k0 = 0, it = 0; k0 < Kdim; k0 += 64, ++it) {
        const int cur = DB ? (it & 1) : 0;
        __syncthreads();                 // DB=0: prev ds_reads done.
                                         // DB=1: buf[cur] staged (vmcnt drain)
                                         //       + buf[cur^1] readers done.
        if (DB) {
            if (k0 + 64 < Kdim) stage(k0 + 64, cur ^ 1);
        } else {
            stage(k0, 0);
            __syncthreads();             // drains vmcnt -> tiles ready
        }
        const char* Sb_ = (const char*)Sm + cur * TB;

        #pragma unroll
        for (int c = 0; c < 2; ++c) {          // k halves of the 64-wide tile
            bf16x8 af[IW], bfr[4];
            #pragma unroll
            for (int i = 0; i < IW; ++i) {
                const int row = wr * (TM / 2) + i * 16 + l15;
                af[i] = *(const bf16x8*)(Sb_ +
                        row * 128 + (((c << 2) + l4) ^ (row & 7)) * 16);
            }
            #pragma unroll
            for (int j = 0; j < 4; ++j) {
                const int row = TM + wc * 64 + j * 16 + l15;
                bfr[j] = *(const bf16x8*)(Sb_ +
                        row * 128 + (((c << 2) + l4) ^ (row & 7)) * 16);
            }
            #pragma unroll
            for (int i = 0; i < IW; ++i)
                #pragma unroll
                for (int j = 0; j < 4; ++j)
                    acc[i][j] = __builtin_amdgcn_mfma_f32_16x16x32_bf16(af[i], bfr[j], acc[i][j], 0, 0, 0);
        }
    }

    // C/D layout: col = lane&15, row = (lane>>4)*4 + reg
    if (MODE == 0) {
        #pragma unroll
        for (int j = 0; j < 4; ++j) {
            const int n = col0 + wc * 64 + j * 16 + l15;
            const float bv_ = bias[n];
            #pragma unroll
            for (int i = 0; i < IW; ++i) {
                #pragma unroll
                for (int r = 0; r < 4; ++r) {
                    const int m = row0 + wr * (TM / 2) + i * 16 + l4 * 4 + r;
                    Cout[(size_t)m * Ndim + n] = acc[i][j][r] + bv_;
                }
            }
        }
    } else {
        #pragma unroll
        for (int j = 0; j < 4; ++j) {
            const int n = col0 + wc * 64 + j * 16 + l15;
            const int which = n / D;           // uniform per block (768 % 128 == 0)
            const int hd = n % D;
            const int h = hd >> 6, d = hd & 63;
            const float bv_ = bias[n];
            if (which == 2) {
                // V transposed [B,H,Dh,T], keys slot-permuted per 32-group:
                // t = h16*16 + g*4 + r  ->  tp = base32 | g*8 + h16*4 + r
                #pragma unroll
                for (int i = 0; i < IW; ++i) {
                    const int m0 = row0 + wr * (TM / 2) + i * 16 + l4 * 4;
                    const int b = m0 >> 11, t = m0 & (T - 1);
                    const int g = (t >> 2) & 3, h16 = (t >> 4) & 1;
                    const int tp = (t & ~31) | (g << 3) | (h16 << 2);
                    float4 v4;
                    v4.x = acc[i][j][0] + bv_; v4.y = acc[i][j][1] + bv_;
                    v4.z = acc[i][j][2] + bv_; v4.w = acc[i][j][3] + bv_;
                    *(ushort4*)&Vo[((size_t)(b * H + h) * Dh + d) * T + tp] = f2bf4(v4);
                }
            } else {
                const float scale = (which == 0) ? SCALE_Q : 1.0f;
                unsigned short* dst = (which == 0) ? Qo : Ko;
                #pragma unroll
                for (int i = 0; i < IW; ++i) {
                    #pragma unroll
                    for (int r = 0; r < 4; ++r) {
                        const int m = row0 + wr * (TM / 2) + i * 16 + l4 * 4 + r;
                        const int b = m >> 11, t = m & (T - 1);
                        dst[((size_t)(b * H + h) * T + t) * Dh + d] =
                            f2bf((acc[i][j][r] + bv_) * scale);
                    }
                }
            }
        }
    }
}

// ---------------------------------------------------------------------------
// Flash attention — proven structure with HOISTED loop-invariant addressing.
// Identical memory ops/bytes to the proven 47.6 us kernel. Key algebra: every
// LDS row is x*16 + l15, so row&7 == l15&7 and the XOR swizzle collapses to
// TWO per-lane constants sw0/sw1; all K/V fragment reads become
// base + rbase + sw{0,1} with the rest folded into ds_read offset
// immediates. Staging source pointers are likewise precomputed per lane and
// advanced by kt. Targets the measured 43% VALUBusy (only ~8 us of it is
// exp2+perm; the rest was per-tile address recomputation at VGPR=44).
// Failed directions (do not retry): wave K-split (R1), QBLK=128 (R3),
// K-from-global (R4/R5), KV-split+combine (R8).
// ---------------------------------------------------------------------------
__global__ __launch_bounds__(256) void attn_kernel(
    const unsigned short* __restrict__ Q, const unsigned short* __restrict__ Kg,
    const unsigned short* __restrict__ Vt, unsigned short* __restrict__ Ctx)
{
    __shared__ unsigned short Ks[2][64 * 64];
    __shared__ unsigned short Vs[2][64 * 64];
    const int bh = blockIdx.y;
    const int q0 = blockIdx.x * 64;
    const int tid = threadIdx.x, lane = tid & 63, wv = tid >> 6;
    const int l15 = lane & 15, l4 = lane >> 4;
    const unsigned short* Qp = Q  + (size_t)bh * T * Dh;
    const unsigned short* Kp = Kg + (size_t)bh * T * Dh;
    const unsigned short* Vp = Vt + (size_t)bh * Dh * T;

    // Q fragments: [n=q=l15][k = l4*8 + j], chunk c covers dh c*32..+31
    bf16x8 qf[2];
    #pragma unroll
    for (int c = 0; c < 2; ++c)
        qf[c] = *(const bf16x8*)&Qp[(size_t)(q0 + wv * 16 + l15) * Dh + c * 32 + l4 * 8];

    const short oneb = (short)0x3F80;     // bf16 1.0
    const bf16x8 onesf = {oneb, oneb, oneb, oneb, oneb, oneb, oneb, oneb};

    // ---- hoisted loop-invariant addressing ----
    // fragment reads: row = x*16 + l15  =>  row&7 == l15&7 for every row.
    const int rbase = l15 * 128;                     // row byte base within tile
    const int sw0   = (l4 ^ (l15 & 7)) * 16;         // swizzled 16B slot, c/G=0
    const int sw1   = ((4 + l4) ^ (l15 & 7)) * 16;   // swizzled 16B slot, c/G=1
    // staging: per-lane source bases (advance K by kt*64, V by kt)
    const int s_offb0 = wv * 2048;                   // chunk i=0 LDS offset
    const int s_offb1 = wv * 2048 + 1024;            // chunk i=1
    const int s_r0 = (s_offb0 + lane * 16) >> 7;
    const int s_r1 = (s_offb1 + lane * 16) >> 7;
    const int s_gc0 = ((((s_offb0 + lane * 16) & 127) >> 4) ^ (s_r0 & 7)) << 3;
    const int s_gc1 = ((((s_offb1 + lane * 16) & 127) >> 4) ^ (s_r1 & 7)) << 3;
    const unsigned short* ksrc0 = Kp + s_r0 * Dh + s_gc0;
    const unsigned short* ksrc1 = Kp + s_r1 * Dh + s_gc1;
    const unsigned short* vsrc0 = Vp + (size_t)s_r0 * T + s_gc0;
    const unsigned short* vsrc1 = Vp + (size_t)s_r1 * T + s_gc1;

    auto load_tiles = [&](int kt, int buf) {
        async_copy16(ksrc0 + kt * Dh, (char*)&Ks[buf][0] + s_offb0);
        async_copy16(ksrc1 + kt * Dh, (char*)&Ks[buf][0] + s_offb1);
        async_copy16(vsrc0 + kt,      (char*)&Vs[buf][0] + s_offb0);
        async_copy16(vsrc1 + kt,      (char*)&Vs[buf][0] + s_offb1);
    };

    load_tiles(0, 0);
    f32x4 o[4], oL;
    #pragma unroll
    for (int nj = 0; nj < 4; ++nj) o[nj] = (f32x4){0.f, 0.f, 0.f, 0.f};
    oL = (f32x4){0.f, 0.f, 0.f, 0.f};

    for (int kt64 = 0; kt64 < T / 64; ++kt64) {
        const int cur = kt64 & 1;
        __syncthreads();     // K/V(kt64) ready (vmcnt drain); buf cur^1 reads done
        if (kt64 + 1 < T / 64) load_tiles((kt64 + 1) * 64, cur ^ 1);

        // per-buffer fragment base pointers (2 adds each; t/nj*2048 -> imm)
        const char* Kb0 = (const char*)&Ks[cur][0] + rbase + sw0;
        const char* Kb1 = (const char*)&Ks[cur][0] + rbase + sw1;
        const char* Vb0 = (const char*)&Vs[cur][0] + rbase + sw0;
        const char* Vb1 = (const char*)&Vs[cur][0] + rbase + sw1;

        // ---- S^T for k16 tiles 0,1 (keys 0..31) ----
        f32x4 Sa[2] = {(f32x4){0.f,0.f,0.f,0.f}, (f32x4){0.f,0.f,0.f,0.f}};
        #pragma unroll
        for (int t = 0; t < 2; ++t) {
            bf16x8 kb0 = *(const bf16x8*)(Kb0 + t * 2048);
            bf16x8 kb1 = *(const bf16x8*)(Kb1 + t * 2048);
            Sa[t] = __builtin_amdgcn_mfma_f32_16x16x32_bf16(kb0, qf[0], Sa[t], 0, 0, 0);
            Sa[t] = __builtin_amdgcn_mfma_f32_16x16x32_bf16(kb1, qf[1], Sa[t], 0, 0, 0);
        }
        #pragma unroll
        for (int t = 0; t < 2; ++t)
            #pragma unroll
            for (int r = 0; r < 4; ++r)
                Sa[t][r] = __builtin_amdgcn_exp2f(Sa[t][r]);
        union { unsigned u[4]; bf16x8 v; } p0;
        p0.u[0] = permpk(Sa[0][1], Sa[0][0]);
        p0.u[1] = permpk(Sa[0][3], Sa[0][2]);
        p0.u[2] = permpk(Sa[1][1], Sa[1][0]);
        p0.u[3] = permpk(Sa[1][3], Sa[1][2]);

        // ---- S^T for k16 tiles 2,3 (keys 32..63) ----
        f32x4 Sb[2] = {(f32x4){0.f,0.f,0.f,0.f}, (f32x4){0.f,0.f,0.f,0.f}};
        #pragma unroll
        for (int t = 0; t < 2; ++t) {
            bf16x8 kb0 = *(const bf16x8*)(Kb0 + (t + 2) * 2048);
            bf16x8 kb1 = *(const bf16x8*)(Kb1 + (t + 2) * 2048);
            Sb[t] = __builtin_amdgcn_mfma_f32_16x16x32_bf16(kb0, qf[0], Sb[t], 0, 0, 0);
            Sb[t] = __builtin_amdgcn_mfma_f32_16x16x32_bf16(kb1, qf[1], Sb[t], 0, 0, 0);
        }

        // ---- PV G0 (overlaps exp2 G1) ----
        oL = __builtin_amdgcn_mfma_f32_16x16x32_bf16(p0.v, onesf, oL, 0, 0, 0);
        #pragma unroll
        for (int nj = 0; nj < 4; ++nj) {
            bf16x8 vb = *(const bf16x8*)(Vb0 + nj * 2048);
            o[nj] = __builtin_amdgcn_mfma_f32_16x16x32_bf16(p0.v, vb, o[nj], 0, 0, 0);
        }

        #pragma unroll
        for (int t = 0; t < 2; ++t)
            #pragma unroll
            for (int r = 0; r < 4; ++r)
                Sb[t][r] = __builtin_amdgcn_exp2f(Sb[t][r]);
        union { unsigned u[4]; bf16x8 v; } p1;
        p1.u[0] = permpk(Sb[0][1], Sb[0][0]);
        p1.u[1] = permpk(Sb[0][3], Sb[0][2]);
        p1.u[2] = permpk(Sb[1][1], Sb[1][0]);
        p1.u[3] = permpk(Sb[1][3], Sb[1][2]);

        // ---- PV G1 ----
        oL = __builtin_amdgcn_mfma_f32_16x16x32_bf16(p1.v, onesf, oL, 0, 0, 0);
        #pragma unroll
        for (int nj = 0; nj < 4; ++nj) {
            bf16x8 vb = *(const bf16x8*)(Vb1 + nj * 2048);
            o[nj] = __builtin_amdgcn_mfma_f32_16x16x32_bf16(p1.v, vb, o[nj], 0, 0, 0);
        }
    }

    // normalize, write ctx bf16 [B, T, D]
    const int b = bh / H, h = bh % H;
    #pragma unroll
    for (int r = 0; r < 4; ++r) {
        const float inv = 1.0f / oL[r];
        const int t = q0 + wv * 16 + l4 * 4 + r;
        #pragma unroll
        for (int nj = 0; nj < 4; ++nj) {
            const int col = h * 64 + nj * 16 + l15;
            Ctx[(size_t)(b * T + t) * D + col] = f2bf(o[nj][r] * inv);
        }
    }
}

// ---------------------------------------------------------------------------
extern "C" void kernel_launch(void* const* d_in, const int* in_sizes, int n_in,
                              void* d_out, int out_size, void* d_ws, size_t ws_size,
                              hipStream_t stream) {
    const float* x  = (const float*)d_in[0];
    const float* Wq = (const float*)d_in[1];
    const float* bq = (const float*)d_in[2];
    const float* Wk = (const float*)d_in[3];
    const float* bk = (const float*)d_in[4];
    const float* Wv = (const float*)d_in[5];
    const float* bv = (const float*)d_in[6];
    const float* Wo = (const float*)d_in[7];
    const float* bo = (const float*)d_in[8];
    float* out = (float*)d_out;

    // workspace carve-up (~34 MB total)
    char* w = (char*)d_ws;
    auto alloc = [&](size_t bytes) {
        char* p = w; w += (bytes + 255) & ~(size_t)255; return p;
    };
    unsigned short* Xb    = (unsigned short*)alloc((size_t)M * D * 2);
    unsigned short* Wqkvb = (unsigned short*)alloc((size_t)NQKV * D * 2);
    unsigned short* Wob   = (unsigned short*)alloc((size_t)D * D * 2);
    float*          biasS = (float*)alloc((size_t)NQKV * 4);
    unsigned short* Qb    = (unsigned short*)alloc((size_t)M * D * 2);
    unsigned short* Kb    = (unsigned short*)alloc((size_t)M * D * 2);
    unsigned short* Vtb   = (unsigned short*)alloc((size_t)M * D * 2);
    unsigned short* Ctxb  = (unsigned short*)alloc((size_t)M * D * 2);

    prep_kernel<<<1024, 256, 0, stream>>>(
        (const float4*)x, (const float4*)Wq, (const float4*)Wk, (const float4*)Wv,
        (const float4*)Wo, bq, bk, bv,
        (ushort4*)Xb, (ushort4*)Wqkvb, (ushort4*)Wob, biasS);

    // QKV GEMM: TM=128, DB=0 (best measured: R6 config; TM=64 R9 and DB=1 R7
    // both regressed/neutral)
    gemm_bt_kernel<1, 128, 0><<<dim3(NQKV / 128, M / 128), 256, 0, stream>>>(
        Xb, Wqkvb, biasS, D, NQKV, nullptr, Qb, Kb, Vtb);

    // attention: proven structure + hoisted addressing, grid (32,24) = 768
    attn_kernel<<<dim3(T / 64, Bb * H), 256, 0, stream>>>(Qb, Kb, Vtb, Ctxb);

    // out-projection: TM=32 + DB=1 (best measured, R6)
    gemm_bt_kernel<0, 32, 1><<<dim3(D / 128, M / 32), 256, 0, stream>>>(
        Ctxb, Wob, bo, D, D, out, nullptr, nullptr, nullptr);
}